// Round 12
// baseline (135.169 us; speedup 1.0000x reference)
//
#include <hip/hip_runtime.h>
#include <hip/hip_fp16.h>

#define NFEAT 128
#define NBUK_MAX 1024   // actual buckets = ceil(50000/64) = 782
#define HB 256          // blocks for hist/scatter passes
#define EPB_MAX 6272    // LDS staging capacity per scatter block (epb = 6250)
#define HPAD 136        // padded LDS row stride in halves (272 B = 17 x 16 B)

typedef __attribute__((ext_vector_type(8))) _Float16 f16x8;
typedef __attribute__((ext_vector_type(4))) float f32x4;

__device__ __forceinline__ uint4 ldz(const char* zb, int s, unsigned qoff) {
    return *reinterpret_cast<const uint4*>(zb + (((unsigned)s << 8) | qoff));
}
__device__ __forceinline__ void fma8(float* acc, const uint4& v, float w) {
    const __half* hp = reinterpret_cast<const __half*>(&v);
#pragma unroll
    for (int k2 = 0; k2 < 8; ++k2)
        acc[k2] = fmaf(w, __half2float(hp[k2]), acc[k2]);
}
// load one 16-edge batch (4 edges per quad-slot) into named registers
__device__ __forceinline__ void loadb(const char* zb, unsigned qoff, int quad,
                                      int src_i, float wgt, int jb,
                                      uint4 (&vv)[4], float (&ww)[4]) {
#pragma unroll
    for (int t = 0; t < 4; ++t) {
        int j = jb + quad + t * 4;
        int s = __shfl(src_i, j);
        ww[t] = __shfl(wgt, j);
        vv[t] = ldz(zb, s, qoff);
    }
}
__device__ __forceinline__ void fmab(float* acc, const uint4 (&vv)[4], const float (&ww)[4]) {
#pragma unroll
    for (int t = 0; t < 4; ++t) fma8(acc, vv[t], ww[t]);
}

// ---------- fused A: role-split blocks — MFMA gemm (782) + edge histogram (256) ----------
__global__ __launch_bounds__(256) void k_fused_a(
    const float* __restrict__ h, const float* __restrict__ W,
    const float* __restrict__ attn_w,
    __half* __restrict__ zh, float* __restrict__ s1, float* __restrict__ s2, int n,
    const int* __restrict__ dst, int* __restrict__ hist, int e, int nbuk, int epb,
    int gemmBlocks)
{
    __shared__ _Float16 smem[192 * HPAD];   // gemm: hsh(64)+wsh(128); hist: lh alias
    const int tid = threadIdx.x;

    if (blockIdx.x >= gemmBlocks) {
        // ---------------- histogram role ----------------
        int* lh = reinterpret_cast<int*>(smem);
        const int b = blockIdx.x - gemmBlocks;
        for (int k = tid; k < nbuk; k += 256) lh[k] = 0;
        __syncthreads();
        const int beg = b * epb, end = min(e, beg + epb);
        for (int i = beg + tid; i < end; i += 256)
            atomicAdd(&lh[dst[i] >> 6], 1);
        __syncthreads();
        for (int k = tid; k < nbuk; k += 256)
            hist[b * nbuk + k] = lh[k];
        return;
    }

    // ---------------- gemm role ----------------
    _Float16* hsh = smem;                  // [64 * HPAD]
    _Float16* wsh = smem + 64 * HPAD;      // [128 * HPAD]
    const int wv = tid >> 6, lane = tid & 63;
    const int nodeBase = blockIdx.x * 64;

    {   // stage W: 128x128 fp32 -> fp16
        const float4* W4 = reinterpret_cast<const float4*>(W);
        for (int t = tid; t < 128 * 32; t += 256) {
            int r = t >> 5, c4 = t & 31;
            float4 v = W4[t];
            _Float16* d = &wsh[r * HPAD + c4 * 4];
            d[0] = (_Float16)v.x; d[1] = (_Float16)v.y;
            d[2] = (_Float16)v.z; d[3] = (_Float16)v.w;
        }
    }
    {   // stage h tile: 64x128 fp32 -> fp16
        const float4* h4 = reinterpret_cast<const float4*>(h);
        for (int t = tid; t < 64 * 32; t += 256) {
            int r = t >> 5, c4 = t & 31;
            int node = nodeBase + r;
            float4 v = (node < n) ? h4[(size_t)node * 32 + c4]
                                  : make_float4(0.f, 0.f, 0.f, 0.f);
            _Float16* d = &hsh[r * HPAD + c4 * 4];
            d[0] = (_Float16)v.x; d[1] = (_Float16)v.y;
            d[2] = (_Float16)v.z; d[3] = (_Float16)v.w;
        }
    }
    __syncthreads();

    const int arow = lane & 15;   // A-row / B-col
    const int kgrp = lane >> 4;   // k-group 0..3
    f32x4 acc[8];
#pragma unroll
    for (int t = 0; t < 8; ++t) acc[t] = (f32x4){0.f, 0.f, 0.f, 0.f};

#pragma unroll
    for (int k0 = 0; k0 < 128; k0 += 32) {
        f16x8 a = *reinterpret_cast<const f16x8*>(
            &hsh[(wv * 16 + arow) * HPAD + k0 + kgrp * 8]);
#pragma unroll
        for (int nt = 0; nt < 8; ++nt) {
            f16x8 b = *reinterpret_cast<const f16x8*>(
                &wsh[(nt * 16 + arow) * HPAD + k0 + kgrp * 8]);
            acc[nt] = __builtin_amdgcn_mfma_f32_16x16x32_f16(a, b, acc[nt], 0, 0, 0);
        }
    }

    // s1/s2 from fp32 accumulators: lane holds cols nt*16+arow, rows kgrp*4+r
    {
        float pr1[4] = {0.f, 0.f, 0.f, 0.f}, pr2[4] = {0.f, 0.f, 0.f, 0.f};
#pragma unroll
        for (int nt = 0; nt < 8; ++nt) {
            float w1v = attn_w[nt * 16 + arow];
            float w2v = attn_w[128 + nt * 16 + arow];
#pragma unroll
            for (int r = 0; r < 4; ++r) {
                pr1[r] += acc[nt][r] * w1v;
                pr2[r] += acc[nt][r] * w2v;
            }
        }
#pragma unroll
        for (int off = 1; off < 16; off <<= 1) {
#pragma unroll
            for (int r = 0; r < 4; ++r) {
                pr1[r] += __shfl_xor(pr1[r], off);
                pr2[r] += __shfl_xor(pr2[r], off);
            }
        }
        if (arow == 0) {
#pragma unroll
            for (int r = 0; r < 4; ++r) {
                int node = nodeBase + wv * 16 + kgrp * 4 + r;
                if (node < n) { s1[node] = pr1[r]; s2[node] = pr2[r]; }
            }
        }
    }

    _Float16* zout = &hsh[wv * 16 * HPAD];
#pragma unroll
    for (int nt = 0; nt < 8; ++nt)
#pragma unroll
        for (int r = 0; r < 4; ++r)
            zout[(kgrp * 4 + r) * HPAD + nt * 16 + arow] = (_Float16)acc[nt][r];

    {
        int node = nodeBase + wv * 16 + arow;
        if (node < n) {
            const uint4* zsrc = reinterpret_cast<const uint4*>(&zout[arow * HPAD + kgrp * 32]);
            uint4* zdst = reinterpret_cast<uint4*>(zh) + (size_t)node * 16 + kgrp * 4;
            uint4 v0 = zsrc[0], v1 = zsrc[1], v2 = zsrc[2], v3 = zsrc[3];
            zdst[0] = v0; zdst[1] = v1; zdst[2] = v2; zdst[3] = v3;
        }
    }
}

// ---------- pass 2: per-bucket exclusive scan over blocks ----------
__global__ __launch_bounds__(256) void k_scan_blocks(const int* __restrict__ hist,
                                                     int* __restrict__ base,
                                                     int* __restrict__ bucket_tot, int nbuk)
{
    __shared__ int wsum[4];
    const int k = blockIdx.x, tid = threadIdx.x;
    int v = hist[tid * nbuk + k];
    int lane = tid & 63, wave = tid >> 6;
    int x = v;
#pragma unroll
    for (int off = 1; off < 64; off <<= 1) {
        int t = __shfl_up(x, off);
        if (lane >= off) x += t;
    }
    if (lane == 63) wsum[wave] = x;
    __syncthreads();
    int wb = 0;
    for (int w = 0; w < wave; ++w) wb += wsum[w];
    base[tid * nbuk + k] = wb + x - v;
    if (tid == 255) bucket_tot[k] = wb + x;
}

// ---------- pass 3: LDS-staged dense scatter; computes bucket_base locally ----------
// packed word: (dst&63)<<22 | etype<<16 | src
__global__ __launch_bounds__(256) void k_sctr(
    const int* __restrict__ src, const int* __restrict__ dst, const int* __restrict__ etype,
    const int* __restrict__ base, const int* __restrict__ bucket_tot,
    int* __restrict__ bucket_base,
    unsigned int* __restrict__ bucket_store, int e, int nbuk, int epb)
{
    __shared__ unsigned int est[EPB_MAX];
    __shared__ unsigned short bkt[EPB_MAX];
    __shared__ int lcnt[NBUK_MAX];
    __shared__ int gbase[NBUK_MAX];
    __shared__ int lcur[NBUK_MAX];
    __shared__ int wsum[4];

    const int b = blockIdx.x, tid = threadIdx.x;
    const int beg = b * epb, end = min(e, beg + epb);
    const int cnt = end - beg;
    const int lane = tid & 63, wv = tid >> 6;
    const int C = (nbuk + 255) / 256;   // <= 4
    const int bi = tid * C;

    for (int k = tid; k < nbuk; k += 256) lcnt[k] = 0;

    // scan 1: exclusive scan of bucket_tot -> bucket prefix
    {
        int vals[4];
        int s = 0;
#pragma unroll
        for (int j = 0; j < 4; ++j) {
            int v = 0;
            if (j < C) {
                int idx = bi + j;
                if (idx < nbuk) v = bucket_tot[idx];
            }
            vals[j] = v; s += v;
        }
        int x = s;
#pragma unroll
        for (int off = 1; off < 64; off <<= 1) {
            int t = __shfl_up(x, off);
            if (lane >= off) x += t;
        }
        if (lane == 63) wsum[wv] = x;
        __syncthreads();
        int wb = 0;
        for (int w = 0; w < wv; ++w) wb += wsum[w];
        int ex = wb + x - s;
#pragma unroll
        for (int j = 0; j < 4; ++j) {
            if (j < C) {
                int idx = bi + j;
                if (idx < nbuk) {
                    gbase[idx] = ex;
                    if (b == 0) bucket_base[idx] = ex;
                    ex += vals[j];
                }
            }
        }
    }
    __syncthreads();

    for (int i = beg + tid; i < end; i += 256)
        atomicAdd(&lcnt[dst[i] >> 6], 1);
    __syncthreads();

    // scan 2: exclusive scan of lcnt; finalize gbase
    {
        int vals[4];
        int s = 0;
#pragma unroll
        for (int j = 0; j < 4; ++j) {
            int v = 0;
            if (j < C) {
                int idx = bi + j;
                if (idx < nbuk) v = lcnt[idx];
            }
            vals[j] = v; s += v;
        }
        int x = s;
#pragma unroll
        for (int off = 1; off < 64; off <<= 1) {
            int t = __shfl_up(x, off);
            if (lane >= off) x += t;
        }
        if (lane == 63) wsum[wv] = x;
        __syncthreads();
        int wb = 0;
        for (int w = 0; w < wv; ++w) wb += wsum[w];
        int ex = wb + x - s;
#pragma unroll
        for (int j = 0; j < 4; ++j) {
            if (j < C) {
                int idx = bi + j;
                if (idx < nbuk) {
                    lcur[idx] = ex;
                    gbase[idx] = gbase[idx] + base[b * nbuk + idx] - ex;
                    ex += vals[j];
                }
            }
        }
    }
    __syncthreads();

    for (int i = beg + tid; i < end; i += 256) {
        int d = dst[i];
        int k = d >> 6;
        unsigned int word =
            (unsigned int)src[i] | ((unsigned int)etype[i] << 16) | ((unsigned int)(d & 63) << 22);
        int pos = atomicAdd(&lcur[k], 1);
        est[pos] = word;
        bkt[pos] = (unsigned short)k;
    }
    __syncthreads();

    for (int j = tid; j < cnt; j += 256)
        bucket_store[gbase[bkt[j]] + j] = est[j];
}

// ---------- pass 4: per-bucket node sort -> CSR + row_start ----------
__global__ __launch_bounds__(256) void k_place(
    const unsigned int* __restrict__ bucket_store, const int* __restrict__ bucket_tot,
    const int* __restrict__ bucket_base,
    int* __restrict__ row_start, unsigned int* __restrict__ edge_list, int n)
{
    __shared__ int cnt64[64];
    const int b = blockIdx.x;
    const int tid = threadIdx.x;
    const int cnt = bucket_tot[b];
    const int base = bucket_base[b];

    if (tid < 64) cnt64[tid] = 0;
    __syncthreads();
    for (int j = tid; j < cnt; j += 256)
        atomicAdd(&cnt64[bucket_store[(size_t)base + j] >> 22], 1);
    __syncthreads();
    if (tid < 64) {
        int v = cnt64[tid];
        int x = v;
#pragma unroll
        for (int off = 1; off < 64; off <<= 1) {
            int t = __shfl_up(x, off);
            if (tid >= off) x += t;
        }
        int node = (b << 6) + tid;
        if (node < n) row_start[node] = base + x - v;
        cnt64[tid] = x - v;
    }
    if (tid == 0) {
        int bnd = (b << 6) + 64;
        if (bnd > n) bnd = n;
        row_start[bnd] = base + cnt;
    }
    __syncthreads();
    for (int j = tid; j < cnt; j += 256) {
        unsigned int pk = bucket_store[(size_t)base + j];
        int pos = base + atomicAdd(&cnt64[pk >> 22], 1);
        edge_list[pos] = pk & 0x3FFFFFu;
    }
}

// ---------- per-node softmax + weighted aggregation; 1 wave = 1 node ----------
// fast path: ALL gather loads issued up front into named register groups
// (no loop back-edge, no register copies -> up to 16 uint4 loads in flight).
__global__ __launch_bounds__(256) void k_aggregate(
    const __half* __restrict__ zh, const float* __restrict__ s1, const float* __restrict__ s2,
    const float* __restrict__ rel_emb, const float* __restrict__ bias,
    const int* __restrict__ row_start, const unsigned int* __restrict__ edge_list,
    float* __restrict__ out, int n)
{
    __shared__ uint2 lds_ws[4][64];   // rare path only
    const int wv   = threadIdx.x >> 6;
    const int lane = threadIdx.x & 63;
    const int node = blockIdx.x * 4 + wv;
    if (node >= n) return;

    const int beg = row_start[node];
    const int end = row_start[node + 1];
    const int deg = end - beg;
    const int quad = lane >> 4;
    const int q    = lane & 15;
    const unsigned qoff = (unsigned)q << 4;
    const char* zb = reinterpret_cast<const char*>(zh);

    float acc[8];
#pragma unroll
    for (int j = 0; j < 8; ++j) acc[j] = 0.f;

    if (deg > 0) {
        const float s2n = s2[node];

        if (deg <= 64) {
            unsigned int pk = 0;
            float ev = -3.4e38f;
            const bool has = lane < deg;
            if (has) {
                pk = edge_list[beg + lane];
                ev = s1[pk & 0xFFFFu] + s2n;
                ev = ev > 0.f ? ev : 0.01f * ev;
            }
            float m = ev;
#pragma unroll
            for (int off = 32; off > 0; off >>= 1)
                m = fmaxf(m, __shfl_xor(m, off));
            float p = has ? __expf(ev - m) : 0.f;
            float den = p;
#pragma unroll
            for (int off = 32; off > 0; off >>= 1)
                den += __shfl_xor(den, off);
            const float inv = 1.f / den;
            const int   src_i = has ? (int)(pk & 0xFFFFu) : 0;
            const float wgt   = has ? rel_emb[pk >> 16] * p * inv : 0.f;

            uint4 v0[4], v1[4], v2[4], v3[4];
            float w0[4], w1[4], w2[4], w3[4];
            // issue ALL loads first (wave-uniform guards; lanes past deg have wgt=0)
            loadb(zb, qoff, quad, src_i, wgt, 0, v0, w0);
            if (deg > 16) loadb(zb, qoff, quad, src_i, wgt, 16, v1, w1);
            if (deg > 32) loadb(zb, qoff, quad, src_i, wgt, 32, v2, w2);
            if (deg > 48) loadb(zb, qoff, quad, src_i, wgt, 48, v3, w3);
            // then consume
            fmab(acc, v0, w0);
            if (deg > 16) fmab(acc, v1, w1);
            if (deg > 32) fmab(acc, v2, w2);
            if (deg > 48) fmab(acc, v3, w3);
        } else {
            // ---- rare path: degree > 64, chunked via LDS
            float mymax = -3.4e38f;
            for (int k = beg + lane; k < end; k += 64) {
                unsigned int pk = edge_list[k];
                float ev = s1[pk & 0xFFFFu] + s2n;
                ev = ev > 0.f ? ev : 0.01f * ev;
                mymax = fmaxf(mymax, ev);
            }
#pragma unroll
            for (int off = 32; off > 0; off >>= 1)
                mymax = fmaxf(mymax, __shfl_xor(mymax, off));
            float mysum = 0.f;
            for (int k = beg + lane; k < end; k += 64) {
                unsigned int pk = edge_list[k];
                float ev = s1[pk & 0xFFFFu] + s2n;
                ev = ev > 0.f ? ev : 0.01f * ev;
                mysum += __expf(ev - mymax);
            }
#pragma unroll
            for (int off = 32; off > 0; off >>= 1)
                mysum += __shfl_xor(mysum, off);
            const float inv = 1.f / mysum;

            for (int cb = beg; cb < end; cb += 64) {
                int k = cb + lane;
                if (k < end) {
                    unsigned int pk = edge_list[k];
                    int s = pk & 0xFFFFu;
                    float ev = s1[s] + s2n;
                    ev = ev > 0.f ? ev : 0.01f * ev;
                    lds_ws[wv][lane] = make_uint2((unsigned)s,
                        __float_as_uint(rel_emb[pk >> 16] * __expf(ev - mymax) * inv));
                }
                int cnt = min(64, end - cb);
#pragma unroll 2
                for (int j = quad; j < cnt; j += 4) {
                    uint2 t = lds_ws[wv][j];
                    float w = __uint_as_float(t.y);
                    uint4 zv = ldz(zb, (int)t.x, qoff);
                    fma8(acc, zv, w);
                }
            }
        }
#pragma unroll
        for (int j = 0; j < 8; ++j) {
            acc[j] += __shfl_xor(acc[j], 16);
            acc[j] += __shfl_xor(acc[j], 32);
        }
    }

    if (quad == 0) {
        const float4* b4 = reinterpret_cast<const float4*>(bias);
        float4 b0 = b4[q * 2], b1 = b4[q * 2 + 1];
        float4* o4 = reinterpret_cast<float4*>(out);
        o4[(size_t)node * 32 + q * 2] =
            make_float4(acc[0] + b0.x, acc[1] + b0.y, acc[2] + b0.z, acc[3] + b0.w);
        o4[(size_t)node * 32 + q * 2 + 1] =
            make_float4(acc[4] + b1.x, acc[5] + b1.y, acc[6] + b1.z, acc[7] + b1.w);
    }
}

extern "C" void kernel_launch(void* const* d_in, const int* in_sizes, int n_in,
                              void* d_out, int out_size, void* d_ws, size_t ws_size,
                              hipStream_t stream) {
    const float* h      = (const float*)d_in[0];
    const float* W      = (const float*)d_in[1];
    const float* attn_w = (const float*)d_in[2];
    const float* rel    = (const float*)d_in[3];
    const float* bias   = (const float*)d_in[4];
    const int*   src    = (const int*)d_in[5];
    const int*   dst    = (const int*)d_in[6];
    const int*   etype  = (const int*)d_in[7];
    const int n = in_sizes[0] / NFEAT;   // 50000
    const int e = in_sizes[5];           // 1600000
    const int nbuk = (n + 63) / 64;      // 782
    const int epb = (e + HB - 1) / HB;   // 6250
    const int gemmBlocks = (n + 63) / 64;
    float* out = (float*)d_out;

    // workspace layout
    char* p = (char*)d_ws;
    __half* zh = (__half*)p;               p += (size_t)n * NFEAT * 2;
    float* s1 = (float*)p;                 p += (size_t)n * 4;
    float* s2 = (float*)p;                 p += (size_t)n * 4;
    int* row_start = (int*)p;              p += (size_t)(n + 1) * 4;
    int* hist       = (int*)p;             p += (size_t)HB * nbuk * 4;
    int* base       = (int*)p;             p += (size_t)HB * nbuk * 4;
    int* bucket_tot = (int*)p;             p += (size_t)nbuk * 4;
    int* bucket_base= (int*)p;             p += (size_t)nbuk * 4;
    unsigned int* edge_list    = (unsigned int*)p;  p += (size_t)e * 4;
    unsigned int* bucket_store = (unsigned int*)p;  p += (size_t)e * 4;

    k_fused_a<<<gemmBlocks + HB, 256, 0, stream>>>(h, W, attn_w, zh, s1, s2, n,
                                                   dst, hist, e, nbuk, epb, gemmBlocks);
    k_scan_blocks<<<nbuk, 256, 0, stream>>>(hist, base, bucket_tot, nbuk);
    k_sctr<<<HB, 256, 0, stream>>>(src, dst, etype, base, bucket_tot, bucket_base,
                                   bucket_store, e, nbuk, epb);
    k_place<<<nbuk, 256, 0, stream>>>(bucket_store, bucket_tot, bucket_base,
                                      row_start, edge_list, n);
    k_aggregate<<<(n + 3) / 4, 256, 0, stream>>>(zh, s1, s2, rel, bias, row_start, edge_list, out, n);
}

// Round 13
// 112.689 us; speedup vs baseline: 1.1995x; 1.1995x over previous
//
#include <hip/hip_runtime.h>
#include <hip/hip_fp16.h>

#define NFEAT 128
#define NBUK_MAX 1024   // actual buckets = ceil(50000/64) = 782
#define HB 256          // blocks for hist/scatter passes
#define EPB_MAX 6272    // LDS staging capacity per scatter block (epb = 6250)
#define HPAD 136        // padded LDS row stride in halves (272 B = 17 x 16 B)

typedef __attribute__((ext_vector_type(8))) _Float16 f16x8;
typedef __attribute__((ext_vector_type(4))) float f32x4;

__device__ __forceinline__ uint4 ldz(const char* zb, int s, unsigned qoff) {
    return *reinterpret_cast<const uint4*>(zb + (((unsigned)s << 8) | qoff));
}
__device__ __forceinline__ void fma8(float* acc, const uint4& v, float w) {
    const __half* hp = reinterpret_cast<const __half*>(&v);
#pragma unroll
    for (int k2 = 0; k2 < 8; ++k2)
        acc[k2] = fmaf(w, __half2float(hp[k2]), acc[k2]);
}

// ---------- fused A: role-split blocks — MFMA gemm (782) + edge histogram (256) ----------
__global__ __launch_bounds__(256) void k_fused_a(
    const float* __restrict__ h, const float* __restrict__ W,
    const float* __restrict__ attn_w,
    __half* __restrict__ zh, float* __restrict__ s1, float* __restrict__ s2, int n,
    const int* __restrict__ dst, int* __restrict__ hist, int e, int nbuk, int epb,
    int gemmBlocks)
{
    __shared__ _Float16 smem[192 * HPAD];   // gemm: hsh(64)+wsh(128); hist: lh alias
    const int tid = threadIdx.x;

    if (blockIdx.x >= gemmBlocks) {
        // ---------------- histogram role ----------------
        int* lh = reinterpret_cast<int*>(smem);
        const int b = blockIdx.x - gemmBlocks;
        for (int k = tid; k < nbuk; k += 256) lh[k] = 0;
        __syncthreads();
        const int beg = b * epb, end = min(e, beg + epb);
        for (int i = beg + tid; i < end; i += 256)
            atomicAdd(&lh[dst[i] >> 6], 1);
        __syncthreads();
        for (int k = tid; k < nbuk; k += 256)
            hist[b * nbuk + k] = lh[k];
        return;
    }

    // ---------------- gemm role ----------------
    _Float16* hsh = smem;                  // [64 * HPAD]
    _Float16* wsh = smem + 64 * HPAD;      // [128 * HPAD]
    const int wv = tid >> 6, lane = tid & 63;
    const int nodeBase = blockIdx.x * 64;

    {   // stage W: 128x128 fp32 -> fp16
        const float4* W4 = reinterpret_cast<const float4*>(W);
        for (int t = tid; t < 128 * 32; t += 256) {
            int r = t >> 5, c4 = t & 31;
            float4 v = W4[t];
            _Float16* d = &wsh[r * HPAD + c4 * 4];
            d[0] = (_Float16)v.x; d[1] = (_Float16)v.y;
            d[2] = (_Float16)v.z; d[3] = (_Float16)v.w;
        }
    }
    {   // stage h tile: 64x128 fp32 -> fp16
        const float4* h4 = reinterpret_cast<const float4*>(h);
        for (int t = tid; t < 64 * 32; t += 256) {
            int r = t >> 5, c4 = t & 31;
            int node = nodeBase + r;
            float4 v = (node < n) ? h4[(size_t)node * 32 + c4]
                                  : make_float4(0.f, 0.f, 0.f, 0.f);
            _Float16* d = &hsh[r * HPAD + c4 * 4];
            d[0] = (_Float16)v.x; d[1] = (_Float16)v.y;
            d[2] = (_Float16)v.z; d[3] = (_Float16)v.w;
        }
    }
    __syncthreads();

    const int arow = lane & 15;   // A-row / B-col
    const int kgrp = lane >> 4;   // k-group 0..3
    f32x4 acc[8];
#pragma unroll
    for (int t = 0; t < 8; ++t) acc[t] = (f32x4){0.f, 0.f, 0.f, 0.f};

#pragma unroll
    for (int k0 = 0; k0 < 128; k0 += 32) {
        f16x8 a = *reinterpret_cast<const f16x8*>(
            &hsh[(wv * 16 + arow) * HPAD + k0 + kgrp * 8]);
#pragma unroll
        for (int nt = 0; nt < 8; ++nt) {
            f16x8 b = *reinterpret_cast<const f16x8*>(
                &wsh[(nt * 16 + arow) * HPAD + k0 + kgrp * 8]);
            acc[nt] = __builtin_amdgcn_mfma_f32_16x16x32_f16(a, b, acc[nt], 0, 0, 0);
        }
    }

    // s1/s2 from fp32 accumulators: lane holds cols nt*16+arow, rows kgrp*4+r
    {
        float pr1[4] = {0.f, 0.f, 0.f, 0.f}, pr2[4] = {0.f, 0.f, 0.f, 0.f};
#pragma unroll
        for (int nt = 0; nt < 8; ++nt) {
            float w1v = attn_w[nt * 16 + arow];
            float w2v = attn_w[128 + nt * 16 + arow];
#pragma unroll
            for (int r = 0; r < 4; ++r) {
                pr1[r] += acc[nt][r] * w1v;
                pr2[r] += acc[nt][r] * w2v;
            }
        }
#pragma unroll
        for (int off = 1; off < 16; off <<= 1) {
#pragma unroll
            for (int r = 0; r < 4; ++r) {
                pr1[r] += __shfl_xor(pr1[r], off);
                pr2[r] += __shfl_xor(pr2[r], off);
            }
        }
        if (arow == 0) {
#pragma unroll
            for (int r = 0; r < 4; ++r) {
                int node = nodeBase + wv * 16 + kgrp * 4 + r;
                if (node < n) { s1[node] = pr1[r]; s2[node] = pr2[r]; }
            }
        }
    }

    _Float16* zout = &hsh[wv * 16 * HPAD];
#pragma unroll
    for (int nt = 0; nt < 8; ++nt)
#pragma unroll
        for (int r = 0; r < 4; ++r)
            zout[(kgrp * 4 + r) * HPAD + nt * 16 + arow] = (_Float16)acc[nt][r];

    {
        int node = nodeBase + wv * 16 + arow;
        if (node < n) {
            const uint4* zsrc = reinterpret_cast<const uint4*>(&zout[arow * HPAD + kgrp * 32]);
            uint4* zdst = reinterpret_cast<uint4*>(zh) + (size_t)node * 16 + kgrp * 4;
            uint4 v0 = zsrc[0], v1 = zsrc[1], v2 = zsrc[2], v3 = zsrc[3];
            zdst[0] = v0; zdst[1] = v1; zdst[2] = v2; zdst[3] = v3;
        }
    }
}

// ---------- pass 2: per-bucket exclusive scan over blocks ----------
__global__ __launch_bounds__(256) void k_scan_blocks(const int* __restrict__ hist,
                                                     int* __restrict__ base,
                                                     int* __restrict__ bucket_tot, int nbuk)
{
    __shared__ int wsum[4];
    const int k = blockIdx.x, tid = threadIdx.x;
    int v = hist[tid * nbuk + k];
    int lane = tid & 63, wave = tid >> 6;
    int x = v;
#pragma unroll
    for (int off = 1; off < 64; off <<= 1) {
        int t = __shfl_up(x, off);
        if (lane >= off) x += t;
    }
    if (lane == 63) wsum[wave] = x;
    __syncthreads();
    int wb = 0;
    for (int w = 0; w < wave; ++w) wb += wsum[w];
    base[tid * nbuk + k] = wb + x - v;
    if (tid == 255) bucket_tot[k] = wb + x;
}

// ---------- pass 3: LDS-staged dense scatter; reuses hist (no re-histogram) ----------
// packed word: (dst&63)<<22 | etype<<16 | src
__global__ __launch_bounds__(256) void k_sctr(
    const int* __restrict__ src, const int* __restrict__ dst, const int* __restrict__ etype,
    const int* __restrict__ hist, const int* __restrict__ base,
    const int* __restrict__ bucket_tot, int* __restrict__ bucket_base,
    unsigned int* __restrict__ bucket_store, int e, int nbuk, int epb)
{
    __shared__ unsigned int est[EPB_MAX];
    __shared__ unsigned short bkt[EPB_MAX];
    __shared__ int gbase[NBUK_MAX];
    __shared__ int lcur[NBUK_MAX];
    __shared__ int wsum[4];

    const int b = blockIdx.x, tid = threadIdx.x;
    const int beg = b * epb, end = min(e, beg + epb);
    const int cnt = end - beg;
    const int lane = tid & 63, wv = tid >> 6;
    const int C = (nbuk + 255) / 256;   // <= 4
    const int bi = tid * C;

    // scan 1: exclusive scan of bucket_tot -> bucket prefix (into gbase)
    {
        int vals[4];
        int s = 0;
#pragma unroll
        for (int j = 0; j < 4; ++j) {
            int v = 0;
            if (j < C) {
                int idx = bi + j;
                if (idx < nbuk) v = bucket_tot[idx];
            }
            vals[j] = v; s += v;
        }
        int x = s;
#pragma unroll
        for (int off = 1; off < 64; off <<= 1) {
            int t = __shfl_up(x, off);
            if (lane >= off) x += t;
        }
        if (lane == 63) wsum[wv] = x;
        __syncthreads();
        int wb = 0;
        for (int w = 0; w < wv; ++w) wb += wsum[w];
        int ex = wb + x - s;
#pragma unroll
        for (int j = 0; j < 4; ++j) {
            if (j < C) {
                int idx = bi + j;
                if (idx < nbuk) {
                    gbase[idx] = ex;
                    if (b == 0) bucket_base[idx] = ex;
                    ex += vals[j];
                }
            }
        }
    }
    __syncthreads();

    // scan 2: exclusive scan of THIS block's histogram row (from hist, no recompute)
    {
        int vals[4];
        int s = 0;
#pragma unroll
        for (int j = 0; j < 4; ++j) {
            int v = 0;
            if (j < C) {
                int idx = bi + j;
                if (idx < nbuk) v = hist[b * nbuk + idx];
            }
            vals[j] = v; s += v;
        }
        int x = s;
#pragma unroll
        for (int off = 1; off < 64; off <<= 1) {
            int t = __shfl_up(x, off);
            if (lane >= off) x += t;
        }
        if (lane == 63) wsum[wv] = x;
        __syncthreads();
        int wb = 0;
        for (int w = 0; w < wv; ++w) wb += wsum[w];
        int ex = wb + x - s;
#pragma unroll
        for (int j = 0; j < 4; ++j) {
            if (j < C) {
                int idx = bi + j;
                if (idx < nbuk) {
                    lcur[idx] = ex;
                    gbase[idx] = gbase[idx] + base[b * nbuk + idx] - ex;
                    ex += vals[j];
                }
            }
        }
    }
    __syncthreads();

    // scatter into LDS (bucket-sorted within block)
    for (int i = beg + tid; i < end; i += 256) {
        int d = dst[i];
        int k = d >> 6;
        unsigned int word =
            (unsigned int)src[i] | ((unsigned int)etype[i] << 16) | ((unsigned int)(d & 63) << 22);
        int pos = atomicAdd(&lcur[k], 1);
        est[pos] = word;
        bkt[pos] = (unsigned short)k;
    }
    __syncthreads();

    // linear drain: dense runs at exact precomputed bases
    for (int j = tid; j < cnt; j += 256)
        bucket_store[gbase[bkt[j]] + j] = est[j];
}

// ---------- pass 4: per-bucket node sort -> CSR + row_start ----------
__global__ __launch_bounds__(256) void k_place(
    const unsigned int* __restrict__ bucket_store, const int* __restrict__ bucket_tot,
    const int* __restrict__ bucket_base,
    int* __restrict__ row_start, unsigned int* __restrict__ edge_list, int n)
{
    __shared__ int cnt64[64];
    const int b = blockIdx.x;
    const int tid = threadIdx.x;
    const int cnt = bucket_tot[b];
    const int base = bucket_base[b];

    if (tid < 64) cnt64[tid] = 0;
    __syncthreads();
    for (int j = tid; j < cnt; j += 256)
        atomicAdd(&cnt64[bucket_store[(size_t)base + j] >> 22], 1);
    __syncthreads();
    if (tid < 64) {
        int v = cnt64[tid];
        int x = v;
#pragma unroll
        for (int off = 1; off < 64; off <<= 1) {
            int t = __shfl_up(x, off);
            if (tid >= off) x += t;
        }
        int node = (b << 6) + tid;
        if (node < n) row_start[node] = base + x - v;
        cnt64[tid] = x - v;
    }
    if (tid == 0) {
        int bnd = (b << 6) + 64;
        if (bnd > n) bnd = n;
        row_start[bnd] = base + cnt;
    }
    __syncthreads();
    for (int j = tid; j < cnt; j += 256) {
        unsigned int pk = bucket_store[(size_t)base + j];
        int pos = base + atomicAdd(&cnt64[pk >> 22], 1);
        edge_list[pos] = pk & 0x3FFFFFu;
    }
}

// ---------- per-node softmax + weighted aggregation; 1 wave = 1 node ----------
// fast path: software-pipelined 4+4 batches, 32-bit offsets (R10 form, 54.8 us).
__global__ __launch_bounds__(256) void k_aggregate(
    const __half* __restrict__ zh, const float* __restrict__ s1, const float* __restrict__ s2,
    const float* __restrict__ rel_emb, const float* __restrict__ bias,
    const int* __restrict__ row_start, const unsigned int* __restrict__ edge_list,
    float* __restrict__ out, int n)
{
    __shared__ uint2 lds_ws[4][64];   // rare path only
    const int wv   = threadIdx.x >> 6;
    const int lane = threadIdx.x & 63;
    const int node = blockIdx.x * 4 + wv;
    if (node >= n) return;

    const int beg = row_start[node];
    const int end = row_start[node + 1];
    const int deg = end - beg;
    const int quad = lane >> 4;
    const int q    = lane & 15;
    const unsigned qoff = (unsigned)q << 4;
    const char* zb = reinterpret_cast<const char*>(zh);

    float acc[8];
#pragma unroll
    for (int j = 0; j < 8; ++j) acc[j] = 0.f;

    if (deg > 0) {
        const float s2n = s2[node];

        if (deg <= 64) {
            unsigned int pk = 0;
            float ev = -3.4e38f;
            const bool has = lane < deg;
            if (has) {
                pk = edge_list[beg + lane];
                ev = s1[pk & 0xFFFFu] + s2n;
                ev = ev > 0.f ? ev : 0.01f * ev;
            }
            float m = ev;
#pragma unroll
            for (int off = 32; off > 0; off >>= 1)
                m = fmaxf(m, __shfl_xor(m, off));
            float p = has ? __expf(ev - m) : 0.f;
            float den = p;
#pragma unroll
            for (int off = 32; off > 0; off >>= 1)
                den += __shfl_xor(den, off);
            const float inv = 1.f / den;
            const int   src_i = has ? (int)(pk & 0xFFFFu) : 0;
            const float wgt   = has ? rel_emb[pk >> 16] * p * inv : 0.f;

            int jb = 0;
            if (deg >= 16) {
                int j0 = quad;
                int   sA = __shfl(src_i, j0),      sB = __shfl(src_i, j0 + 4);
                int   sC = __shfl(src_i, j0 + 8),  sD = __shfl(src_i, j0 + 12);
                float wA = __shfl(wgt, j0),        wB = __shfl(wgt, j0 + 4);
                float wC = __shfl(wgt, j0 + 8),    wD = __shfl(wgt, j0 + 12);
                uint4 vA = ldz(zb, sA, qoff), vB = ldz(zb, sB, qoff);
                uint4 vC = ldz(zb, sC, qoff), vD = ldz(zb, sD, qoff);
                for (; jb + 32 <= deg; jb += 16) {
                    int j1 = jb + 16 + quad;
                    int   tA = __shfl(src_i, j1),      tB = __shfl(src_i, j1 + 4);
                    int   tC = __shfl(src_i, j1 + 8),  tD = __shfl(src_i, j1 + 12);
                    float xA = __shfl(wgt, j1),        xB = __shfl(wgt, j1 + 4);
                    float xC = __shfl(wgt, j1 + 8),    xD = __shfl(wgt, j1 + 12);
                    uint4 uA = ldz(zb, tA, qoff), uB = ldz(zb, tB, qoff);
                    uint4 uC = ldz(zb, tC, qoff), uD = ldz(zb, tD, qoff);
                    fma8(acc, vA, wA); fma8(acc, vB, wB);
                    fma8(acc, vC, wC); fma8(acc, vD, wD);
                    vA = uA; vB = uB; vC = uC; vD = uD;
                    wA = xA; wB = xB; wC = xC; wD = xD;
                }
                fma8(acc, vA, wA); fma8(acc, vB, wB);
                fma8(acc, vC, wC); fma8(acc, vD, wD);
                jb += 16;
            }
            for (; jb < deg; jb += 4) {
                const int j = jb + quad;   // j < 64 always; wgt=0 beyond deg
                int   sj = __shfl(src_i, j);
                float wj = __shfl(wgt, j);
                uint4 zv = ldz(zb, sj, qoff);
                fma8(acc, zv, wj);
            }
        } else {
            // ---- rare path: degree > 64, chunked via LDS
            float mymax = -3.4e38f;
            for (int k = beg + lane; k < end; k += 64) {
                unsigned int pk = edge_list[k];
                float ev = s1[pk & 0xFFFFu] + s2n;
                ev = ev > 0.f ? ev : 0.01f * ev;
                mymax = fmaxf(mymax, ev);
            }
#pragma unroll
            for (int off = 32; off > 0; off >>= 1)
                mymax = fmaxf(mymax, __shfl_xor(mymax, off));
            float mysum = 0.f;
            for (int k = beg + lane; k < end; k += 64) {
                unsigned int pk = edge_list[k];
                float ev = s1[pk & 0xFFFFu] + s2n;
                ev = ev > 0.f ? ev : 0.01f * ev;
                mysum += __expf(ev - mymax);
            }
#pragma unroll
            for (int off = 32; off > 0; off >>= 1)
                mysum += __shfl_xor(mysum, off);
            const float inv = 1.f / mysum;

            for (int cb = beg; cb < end; cb += 64) {
                int k = cb + lane;
                if (k < end) {
                    unsigned int pk = edge_list[k];
                    int s = pk & 0xFFFFu;
                    float ev = s1[s] + s2n;
                    ev = ev > 0.f ? ev : 0.01f * ev;
                    lds_ws[wv][lane] = make_uint2((unsigned)s,
                        __float_as_uint(rel_emb[pk >> 16] * __expf(ev - mymax) * inv));
                }
                int cnt = min(64, end - cb);
#pragma unroll 2
                for (int j = quad; j < cnt; j += 4) {
                    uint2 t = lds_ws[wv][j];
                    float w = __uint_as_float(t.y);
                    uint4 zv = ldz(zb, (int)t.x, qoff);
                    fma8(acc, zv, w);
                }
            }
        }
#pragma unroll
        for (int j = 0; j < 8; ++j) {
            acc[j] += __shfl_xor(acc[j], 16);
            acc[j] += __shfl_xor(acc[j], 32);
        }
    }

    if (quad == 0) {
        const float4* b4 = reinterpret_cast<const float4*>(bias);
        float4 b0 = b4[q * 2], b1 = b4[q * 2 + 1];
        float4* o4 = reinterpret_cast<float4*>(out);
        o4[(size_t)node * 32 + q * 2] =
            make_float4(acc[0] + b0.x, acc[1] + b0.y, acc[2] + b0.z, acc[3] + b0.w);
        o4[(size_t)node * 32 + q * 2 + 1] =
            make_float4(acc[4] + b1.x, acc[5] + b1.y, acc[6] + b1.z, acc[7] + b1.w);
    }
}

extern "C" void kernel_launch(void* const* d_in, const int* in_sizes, int n_in,
                              void* d_out, int out_size, void* d_ws, size_t ws_size,
                              hipStream_t stream) {
    const float* h      = (const float*)d_in[0];
    const float* W      = (const float*)d_in[1];
    const float* attn_w = (const float*)d_in[2];
    const float* rel    = (const float*)d_in[3];
    const float* bias   = (const float*)d_in[4];
    const int*   src    = (const int*)d_in[5];
    const int*   dst    = (const int*)d_in[6];
    const int*   etype  = (const int*)d_in[7];
    const int n = in_sizes[0] / NFEAT;   // 50000
    const int e = in_sizes[5];           // 1600000
    const int nbuk = (n + 63) / 64;      // 782
    const int epb = (e + HB - 1) / HB;   // 6250
    const int gemmBlocks = (n + 63) / 64;
    float* out = (float*)d_out;

    // workspace layout
    char* p = (char*)d_ws;
    __half* zh = (__half*)p;               p += (size_t)n * NFEAT * 2;
    float* s1 = (float*)p;                 p += (size_t)n * 4;
    float* s2 = (float*)p;                 p += (size_t)n * 4;
    int* row_start = (int*)p;              p += (size_t)(n + 1) * 4;
    int* hist       = (int*)p;             p += (size_t)HB * nbuk * 4;
    int* base       = (int*)p;             p += (size_t)HB * nbuk * 4;
    int* bucket_tot = (int*)p;             p += (size_t)nbuk * 4;
    int* bucket_base= (int*)p;             p += (size_t)nbuk * 4;
    unsigned int* edge_list    = (unsigned int*)p;  p += (size_t)e * 4;
    unsigned int* bucket_store = (unsigned int*)p;  p += (size_t)e * 4;

    k_fused_a<<<gemmBlocks + HB, 256, 0, stream>>>(h, W, attn_w, zh, s1, s2, n,
                                                   dst, hist, e, nbuk, epb, gemmBlocks);
    k_scan_blocks<<<nbuk, 256, 0, stream>>>(hist, base, bucket_tot, nbuk);
    k_sctr<<<HB, 256, 0, stream>>>(src, dst, etype, hist, base, bucket_tot, bucket_base,
                                   bucket_store, e, nbuk, epb);
    k_place<<<nbuk, 256, 0, stream>>>(bucket_store, bucket_tot, bucket_base,
                                      row_start, edge_list, n);
    k_aggregate<<<(n + 3) / 4, 256, 0, stream>>>(zh, s1, s2, rel, bias, row_start, edge_list, out, n);
}